// Round 3
// baseline (1274.926 us; speedup 1.0000x reference)
//
#include <hip/hip_runtime.h>
#include <math.h>

#define BS 64
#define BT 64
#define TSL 128   // T_S
#define TTL 128   // T_T
#define QD 64

// ---------------------------------------------------------------------------
// Fused kernel: one block per (s,t) pair.
//  Phase 1: stage xs[s], xt[t] into LDS transposed (k-major).
//  Phase 2: row/col squared norms.
//  Phase 3: 128x128x64 f32 GEMM (8x8 register tiles) -> C = sqrt(max(d2,1e-12)) in LDS.
//  Phase 4: DTW forward DP over anti-diagonals, one wave, carrying (acc, S)
//           where S[i][j] = C[i][j] + S[greedy-pred(i,j)].  dtw_cost = S_pred at
//           (127,127)  (path excludes the end cell, includes origin) — this is
//           bit-identical to the reference's backtrack because the backtrack's
//           argmin over [diag, up, left] (tie-break in that order) is exactly
//           the argmin the forward DP evaluates at each cell.
//  dtw_cost is parked in out[2 + s*64 + t] (the gamma slots, overwritten later
//  by the sinkhorn kernel) — avoids relying on ws_size.
// ---------------------------------------------------------------------------
__global__ __launch_bounds__(256)
void fused_dtw_kernel(const float* __restrict__ xs, const float* __restrict__ xt,
                      float* __restrict__ dtw_out) {
    extern __shared__ float sm[];
    float* xsT = sm;                      // [64][128]  xsT[k][i]
    float* xtT = sm + QD * TSL;           // [64][128]
    float* Cm  = sm + 2 * QD * TSL;       // [128][128]
    float* x2  = Cm + TSL * TTL;          // [128]
    float* y2  = x2 + TSL;                // [128]

    const int p = blockIdx.x;
    const int s = p >> 6, t = p & 63;
    const float4* xsp = (const float4*)(xs + (size_t)s * TSL * QD);
    const float4* xtp = (const float4*)(xt + (size_t)t * TTL * QD);
    const int tid = threadIdx.x;

    // ---- Phase 1: stage (8192 floats each side = 2048 float4; 8 per thread)
#pragma unroll
    for (int r = 0; r < 8; ++r) {
        int f4 = tid + 256 * r;        // 0..2047
        int i  = f4 >> 4;              // row (16 float4 per 64-float row)
        int k  = (f4 & 15) << 2;       // feature base
        float4 v = xsp[f4];
        xsT[(k + 0) * TSL + i] = v.x;
        xsT[(k + 1) * TSL + i] = v.y;
        xsT[(k + 2) * TSL + i] = v.z;
        xsT[(k + 3) * TSL + i] = v.w;
        float4 w = xtp[f4];
        xtT[(k + 0) * TTL + i] = w.x;
        xtT[(k + 1) * TTL + i] = w.y;
        xtT[(k + 2) * TTL + i] = w.z;
        xtT[(k + 3) * TTL + i] = w.w;
    }
    __syncthreads();

    // ---- Phase 2: norms (waves 0/1 -> x2, waves 2/3 -> y2)
    if (tid < 128) {
        float a = 0.f;
#pragma unroll 8
        for (int k = 0; k < QD; ++k) { float v = xsT[k * TSL + tid]; a = fmaf(v, v, a); }
        x2[tid] = a;
    } else {
        int j = tid - 128;
        float a = 0.f;
#pragma unroll 8
        for (int k = 0; k < QD; ++k) { float v = xtT[k * TTL + j]; a = fmaf(v, v, a); }
        y2[j] = a;
    }
    __syncthreads();

    // ---- Phase 3: GEMM, 16x16 threads x 8x8 tile
    {
        const int tx = tid & 15, ty = tid >> 4;
        const int ib = ty * 8, jb = tx * 8;
        float acc[8][8];
#pragma unroll
        for (int r = 0; r < 8; ++r)
#pragma unroll
            for (int c = 0; c < 8; ++c) acc[r][c] = 0.f;

        for (int k = 0; k < QD; ++k) {
            float4 a0 = *(const float4*)&xsT[k * TSL + ib];
            float4 a1 = *(const float4*)&xsT[k * TSL + ib + 4];
            float4 b0 = *(const float4*)&xtT[k * TTL + jb];
            float4 b1 = *(const float4*)&xtT[k * TTL + jb + 4];
            float a[8] = {a0.x, a0.y, a0.z, a0.w, a1.x, a1.y, a1.z, a1.w};
            float b[8] = {b0.x, b0.y, b0.z, b0.w, b1.x, b1.y, b1.z, b1.w};
#pragma unroll
            for (int r = 0; r < 8; ++r)
#pragma unroll
                for (int c = 0; c < 8; ++c)
                    acc[r][c] = fmaf(a[r], b[c], acc[r][c]);
        }
#pragma unroll
        for (int r = 0; r < 8; ++r) {
            float xr = x2[ib + r];
#pragma unroll
            for (int c = 0; c < 8; ++c) {
                float d2 = xr + y2[jb + c] - 2.f * acc[r][c];
                Cm[(ib + r) * TTL + jb + c] = sqrtf(fmaxf(d2, 1e-12f));
            }
        }
    }
    __syncthreads();

    // ---- Phase 4: DTW DP (wave 0 only). Lane l owns columns l and l+64.
    if (tid < 64) {
        const int l = tid;
        const float INF = __builtin_inff();
        // acc state: A = diagonal d-2, B = diagonal d-1
        float aA0 = INF, aA1 = INF, aB0 = INF, aB1 = INF;
        float sB0 = 0.f, sB1 = 0.f;
        // shuffles of the A-state saved from the previous step
        float upA0 = INF, upA1 = INF, upSA0 = 0.f, upSA1 = 0.f;
        float bcA0 = INF, bcSA0 = 0.f;
        float dtw = 0.f;

        for (int d = 0; d < 255; ++d) {
            float upB0  = __shfl_up(aB0, 1);
            float upB1  = __shfl_up(aB1, 1);
            float upSB0 = __shfl_up(sB0, 1);
            float upSB1 = __shfl_up(sB1, 1);
            float bcB0  = __shfl(aB0, 63);
            float bcSB0 = __shfl(sB0, 63);

            // ---- cell 0: (i0, l), i0 = d - l
            int  i0 = d - l;
            bool v0 = (i0 >= 0) && (i0 <= 127);
            int  i0c = i0 < 0 ? 0 : (i0 > 127 ? 127 : i0);
            float c0 = Cm[i0c * TTL + l];
            float diag0  = (l == 0) ? INF : upA0;    // acc[i0-1][l-1]
            float sdiag0 = (l == 0) ? 0.f : upSA0;
            float up0 = aB0,  sup0 = sB0;            // acc[i0-1][l]
            float left0  = (l == 0) ? INF : upB0;    // acc[i0][l-1]
            float sleft0 = (l == 0) ? 0.f : upSB0;
            if (d == 0 && l == 0) { diag0 = 0.f; sdiag0 = 0.f; }  // virtual origin
            bool seld0 = (diag0 <= up0) && (diag0 <= left0);
            bool selu0 = (up0 <= left0);
            float m0  = fminf(diag0, fminf(up0, left0));
            float sp0 = seld0 ? sdiag0 : (selu0 ? sup0 : sleft0);
            float na0 = v0 ? (c0 + m0)  : INF;
            float ns0 = v0 ? (c0 + sp0) : 0.f;

            // ---- cell 1: (i1, l+64), i1 = d - l - 64
            int  i1 = d - l - 64;
            bool v1 = (i1 >= 0) && (i1 <= 127);
            int  i1c = i1 < 0 ? 0 : (i1 > 127 ? 127 : i1);
            float c1 = Cm[i1c * TTL + l + 64];
            float diag1  = (l == 0) ? bcA0  : upA1;  // acc[i1-1][l+63]
            float sdiag1 = (l == 0) ? bcSA0 : upSA1;
            float up1 = aB1,  sup1 = sB1;
            float left1  = (l == 0) ? bcB0  : upB1;
            float sleft1 = (l == 0) ? bcSB0 : upSB1;
            bool seld1 = (diag1 <= up1) && (diag1 <= left1);
            bool selu1 = (up1 <= left1);
            float m1  = fminf(diag1, fminf(up1, left1));
            float sp1 = seld1 ? sdiag1 : (selu1 ? sup1 : sleft1);
            float na1 = v1 ? (c1 + m1)  : INF;
            float ns1 = v1 ? (c1 + sp1) : 0.f;

            if (v1) dtw = sp1;   // last valid write on lane 63 is (127,127) at d=254

            // rotate
            aA0 = aB0; aA1 = aB1;
            upA0 = upB0; upA1 = upB1; upSA0 = upSB0; upSA1 = upSB1;
            bcA0 = bcB0; bcSA0 = bcSB0;
            aB0 = na0; aB1 = na1; sB0 = ns0; sB1 = ns1;
        }
        if (l == 63) dtw_out[p] = dtw;
    }
}

// ---------------------------------------------------------------------------
// Sinkhorn (log-domain, 300 iters, matches reference) + final reductions.
// One block, 256 threads. Row s handled by 4 lanes (shfl_xor 1,2 reductions).
// Reads dtw from out[2..] (parked there by fused_dtw_kernel), then overwrites
// those slots with gamma.  All dtw reads complete before the first
// __syncthreads(); gamma writes happen only after the iteration loop.
// ---------------------------------------------------------------------------
__global__ __launch_bounds__(256)
void sinkhorn_kernel(const float* __restrict__ sim, float* out) {
    __shared__ float M[64 * 64];
    __shared__ float Mt[64 * 64];
    __shared__ float fv[64], gv[64];
    __shared__ float red[4], redB[4];
    __shared__ float epsS[2];
    const int tid = threadIdx.x;

    float lmax = -1e30f;
#pragma unroll
    for (int r = 0; r < 16; ++r) {
        int idx = tid + 256 * r;                      // idx = s*64 + t
        float m = out[2 + idx] + 0.1f * sim[idx];     // cost_OT = ALPHA*dtw + BETA*sim
        M[idx] = m;
        Mt[(idx & 63) * 64 + (idx >> 6)] = m;
        lmax = fmaxf(lmax, m);
    }
#pragma unroll
    for (int o = 32; o > 0; o >>= 1) lmax = fmaxf(lmax, __shfl_xor(lmax, o));
    if ((tid & 63) == 0) red[tid >> 6] = lmax;
    if (tid < 64) { fv[tid] = 0.f; gv[tid] = 0.f; }
    __syncthreads();
    if (tid == 0) {
        float mx = fmaxf(fmaxf(red[0], red[1]), fmaxf(red[2], red[3]));
        epsS[0] = 0.02f * mx;
        epsS[1] = 1.0f / epsS[0];
    }
    __syncthreads();
    const float eps = epsS[0], ie = epsS[1];
    const float elog = eps * (-4.1588830833596715f);   // eps * log(1/64)

    const int sr = tid >> 2;        // row/col this group handles
    const int q  = tid & 3;
    const int tb = q * 16;

    for (int it = 0; it < 300; ++it) {
        // f-update (rows of M)
        float vals[16];
        float mx = -1e30f;
#pragma unroll
        for (int r = 0; r < 16; ++r) {
            float v = (gv[tb + r] - M[sr * 64 + tb + r]) * ie;
            vals[r] = v;
            mx = fmaxf(mx, v);
        }
        mx = fmaxf(mx, __shfl_xor(mx, 1));
        mx = fmaxf(mx, __shfl_xor(mx, 2));
        float sum = 0.f;
#pragma unroll
        for (int r = 0; r < 16; ++r) sum += __expf(vals[r] - mx);
        sum += __shfl_xor(sum, 1);
        sum += __shfl_xor(sum, 2);
        if (q == 0) fv[sr] = elog - eps * (__logf(sum) + mx);
        __syncthreads();

        // g-update (rows of Mt = columns of M), uses the NEW f
        float mx2 = -1e30f;
#pragma unroll
        for (int r = 0; r < 16; ++r) {
            float v = (fv[tb + r] - Mt[sr * 64 + tb + r]) * ie;
            vals[r] = v;
            mx2 = fmaxf(mx2, v);
        }
        mx2 = fmaxf(mx2, __shfl_xor(mx2, 1));
        mx2 = fmaxf(mx2, __shfl_xor(mx2, 2));
        float sum2 = 0.f;
#pragma unroll
        for (int r = 0; r < 16; ++r) sum2 += __expf(vals[r] - mx2);
        sum2 += __shfl_xor(sum2, 1);
        sum2 += __shfl_xor(sum2, 2);
        if (q == 0) gv[sr] = elog - eps * (__logf(sum2) + mx2);
        __syncthreads();
    }

    // gamma + final reductions.  alpha uses dtw = M - 0.1*sim (exact reconstruction).
    float la = 0.f, lb = 0.f;
#pragma unroll
    for (int r = 0; r < 16; ++r) {
        int idx = tid + 256 * r;
        float Mv = M[idx];
        float sv = sim[idx];
        float ga = __expf((fv[idx >> 6] + gv[idx & 63] - Mv) * ie);
        out[2 + idx] = ga;
        la = fmaf(ga, Mv - 0.1f * sv, la);
        lb = fmaf(ga, sv, lb);
    }
#pragma unroll
    for (int o = 32; o > 0; o >>= 1) {
        la += __shfl_xor(la, o);
        lb += __shfl_xor(lb, o);
    }
    if ((tid & 63) == 0) { red[tid >> 6] = la; redB[tid >> 6] = lb; }
    __syncthreads();
    if (tid == 0) {
        float A  = red[0] + red[1] + red[2] + red[3];
        float Bc = redB[0] + redB[1] + redB[2] + redB[3];
        // length = (Q + Q)/2 = 64
        out[0] = A * (1.0f / 64.0f);
        out[1] = 0.1f * Bc * (1.0f / 64.0f);
    }
}

extern "C" void kernel_launch(void* const* d_in, const int* in_sizes, int n_in,
                              void* d_out, int out_size, void* d_ws, size_t ws_size,
                              hipStream_t stream) {
    const float* xs  = (const float*)d_in[0];   // (64,128,64) f32
    const float* xt  = (const float*)d_in[1];   // (64,128,64) f32
    const float* sim = (const float*)d_in[3];   // (64,64) f32  (labels d_in[2] unused)
    float* out = (float*)d_out;                 // [alpha, beta, gamma(4096)]
    (void)d_ws; (void)ws_size;                  // deliberately unused (size unknown)

    // 129 KB dynamic LDS: xsT(32K) + xtT(32K) + C(64K) + norms(1K)
    const int smem = (2 * QD * TSL + TSL * TTL + 2 * TSL) * (int)sizeof(float);
    hipFuncSetAttribute((const void*)fused_dtw_kernel,
                        hipFuncAttributeMaxDynamicSharedMemorySize, smem);

    hipLaunchKernelGGL(fused_dtw_kernel, dim3(BS * BT), dim3(256), smem, stream,
                       xs, xt, out + 2);
    hipLaunchKernelGGL(sinkhorn_kernel, dim3(1), dim3(256), 0, stream,
                       sim, out);
}

// Round 4
// 809.905 us; speedup vs baseline: 1.5742x; 1.5742x over previous
//
#include <hip/hip_runtime.h>
#include <math.h>

#define BS 64
#define BT 64
#define TSL 128   // T_S
#define TTL 128   // T_T
#define QD 64
#define CPAIR 16512   // compact-diagonal bf16 elems per pair (diagonals padded to even length)

using bf16x8 = __attribute__((ext_vector_type(8))) short;
using f32x4  = __attribute__((ext_vector_type(4))) float;

// f32 -> bf16 bits, round-to-nearest-even (finite inputs only)
__device__ __forceinline__ unsigned short f2bf(float f) {
    unsigned u = __float_as_uint(f);
    u += 0x7FFFu + ((u >> 16) & 1u);
    return (unsigned short)(u >> 16);
}

// compact-diagonal index: diagonals d=0..254, each padded to even length,
// plus a 1-slot front pad when jstart(d) is odd so cell j has parity j&1.
// cidx(d, j) is even for even j  =>  (c_even, c_odd) read as one aligned u32.
__device__ __forceinline__ int cidx(int d, int j) {
    int off  = (d <= 128) ? ((d * (d + 1)) >> 1)
                          : (8256 + 127 * (d - 128) - (((d - 128) * (d - 129)) >> 1));
    int poff = off + ((d + 1) >> 1);
    int js   = d - 127; js = js < 0 ? 0 : js;
    return poff + (j - js) + (js & 1);
}

__device__ __forceinline__ bf16x8 load_frag(const float* p) {
    float4 u = *(const float4*)p;
    float4 v = *(const float4*)(p + 4);
    bf16x8 f;
    f[0] = (short)f2bf(u.x); f[1] = (short)f2bf(u.y);
    f[2] = (short)f2bf(u.z); f[3] = (short)f2bf(u.w);
    f[4] = (short)f2bf(v.x); f[5] = (short)f2bf(v.y);
    f[6] = (short)f2bf(v.z); f[7] = (short)f2bf(v.w);
    return f;
}

// ---------------------------------------------------------------------------
// Fused kernel: 1024 blocks x 256 threads; block b handles s = b>>4 and the
// four targets t = (b&15)*4 + w (wave w owns pair w end-to-end).
//  Phase 0: norms (all threads) + one barrier.
//  Phase 1 (per wave): 128x128x64 GEMM via mfma_f32_16x16x32_bf16, fragments
//           loaded from global f32 (L1/L2-resident) with inline bf16 cvt.
//           C = sqrt(max(x2+y2-2ab,1e-12)) stored bf16 compact-diagonal in LDS.
//  Phase 2 (per wave): DTW forward DP, lane l owns columns 2l,2l+1.
//           dtw = min(acc[126][126], acc[126][127], acc[127][126])  (the
//           greedy-backtrack path cost equals acc at the chosen predecessor
//           of the end cell; value-min needs no tie-break).
// No d_ws use: dtw parked in out[2..] gamma slots.
// ---------------------------------------------------------------------------
__global__ __launch_bounds__(256)
void fused_dtw_kernel(const float* __restrict__ xs, const float* __restrict__ xt,
                      float* __restrict__ dtw_out) {
    extern __shared__ char smraw[];
    unsigned short* Cd = (unsigned short*)smraw;          // 4 * CPAIR bf16
    float* x2 = (float*)(smraw + 4 * CPAIR * 2);          // [128]
    float* y2 = x2 + 128;                                 // [4*128]

    const int b   = blockIdx.x;
    const int s   = b >> 4;
    const int t0  = (b & 15) * 4;
    const int tid = threadIdx.x;
    const int w    = tid >> 6;
    const int lane = tid & 63;

    const float* XS = xs + (size_t)s * TSL * QD;

    // ---- Phase 0: squared norms (640 dot-products over 256 threads)
    for (int e = tid; e < 640; e += 256) {
        const float* src = (e < 128)
            ? (XS + e * QD)
            : (xt + (size_t)(t0 + ((e - 128) >> 7)) * TTL * QD + ((e - 128) & 127) * QD);
        float a = 0.f;
        const float4* pp = (const float4*)src;
#pragma unroll
        for (int kk = 0; kk < 16; ++kk) {
            float4 vv = pp[kk];
            a = fmaf(vv.x, vv.x, a); a = fmaf(vv.y, vv.y, a);
            a = fmaf(vv.z, vv.z, a); a = fmaf(vv.w, vv.w, a);
        }
        if (e < 128) x2[e] = a; else y2[e - 128] = a;
    }
    __syncthreads();

    // ---- Phase 1: per-wave MFMA GEMM -> bf16 compact-diag C in LDS
    const float* XT = xt + (size_t)(t0 + w) * TTL * QD;
    unsigned short* Cw = Cd + w * CPAIR;
    const int r16 = lane & 15;   // A-row / B-col within 16-tile
    const int kq  = lane >> 4;   // k-quad

    for (int i0 = 0; i0 < 128; i0 += 16) {
        bf16x8 Af[2];
#pragma unroll
        for (int kh = 0; kh < 2; ++kh)
            Af[kh] = load_frag(XS + (i0 + r16) * QD + kh * 32 + kq * 8);
        float xr[4];
#pragma unroll
        for (int r = 0; r < 4; ++r) xr[r] = x2[i0 + kq * 4 + r];

        for (int j0 = 0; j0 < 128; j0 += 16) {
            bf16x8 Bf[2];
#pragma unroll
            for (int kh = 0; kh < 2; ++kh)
                Bf[kh] = load_frag(XT + (j0 + r16) * QD + kh * 32 + kq * 8);
            f32x4 acc = {0.f, 0.f, 0.f, 0.f};
            acc = __builtin_amdgcn_mfma_f32_16x16x32_bf16(Af[0], Bf[0], acc, 0, 0, 0);
            acc = __builtin_amdgcn_mfma_f32_16x16x32_bf16(Af[1], Bf[1], acc, 0, 0, 0);
            float yc = y2[w * 128 + j0 + r16];
            int jj = j0 + r16;
            int ib = i0 + kq * 4;
#pragma unroll
            for (int r = 0; r < 4; ++r) {
                float d2 = xr[r] + yc - 2.f * acc[r];
                float c  = sqrtf(fmaxf(d2, 1e-12f));
                Cw[cidx(ib + r + jj, jj)] = f2bf(c);
            }
        }
    }

    // ---- Phase 2: per-wave DTW DP (lane l owns columns 2l, 2l+1)
    {
        const int l = lane;
        const float INF = __builtin_inff();

        // peel d = 0: only cell (0,0) (lane 0 even); acc = C(0,0) + virtual origin 0
        unsigned cw0 = *(const unsigned*)Cd;  // pair 0 slot... (use own pair:)
        cw0 = *(const unsigned*)(Cw);         // slots [0,1]: [C(0,0), pad]
        float c00 = __uint_as_float(cw0 << 16);
        float eB   = (l == 0) ? c00 : INF;    // even acc at diag d-1
        float oB   = INF;                     // odd  acc at diag d-1
        float eA   = INF;                     // even acc at diag d-2
        float shoA = INF;                     // lane-1 odd acc at diag d-2

        for (int d = 1; d <= 253; ++d) {
            float shoB = __shfl_up(oB, 1);
            if (l == 0) shoB = INF;

            // wave-uniform diagonal constants
            int off  = (d <= 128) ? ((d * (d + 1)) >> 1)
                                  : (8256 + 127 * (d - 128) - (((d - 128) * (d - 129)) >> 1));
            int poff = off + ((d + 1) >> 1);
            int js   = d - 127; js = js < 0 ? 0 : js;
            int ide  = poff + 2 * l - js + (js & 1);
            ide = ide < 16510 ? ide : 16510;

            unsigned cw = *(const unsigned*)(Cw + ide);
            float c_e = __uint_as_float(cw << 16);
            float c_o = __uint_as_float(cw & 0xFFFF0000u);

            int ie = d - 2 * l;   // even-cell row; odd-cell row = ie-1
            float ne = (ie >= 0 && ie <= 127) ? c_e + fminf(shoA, fminf(eB, shoB)) : INF;
            float no = (ie >= 1 && ie <= 128) ? c_o + fminf(eA, fminf(oB, eB))     : INF;

            eA = eB; eB = ne; oB = no; shoA = shoB;
        }
        // after d=253: eA=(126,126), eB=(127,126), oB=(126,127)
        if (l == 63) dtw_out[s * 64 + t0 + w] = fminf(fminf(eA, eB), oB);
    }
}

// ---------------------------------------------------------------------------
// Sinkhorn (log-domain, 300 iters, exp2-domain LSE) + final reductions.
// One block, 256 threads.  M rows/cols/sim cached in REGISTERS (no per-iter
// M traffic); only the 64-vectors f,g cross waves via LDS.
// Reads dtw from out[2..]; overwrites those slots with gamma at the end.
// ---------------------------------------------------------------------------
__global__ __launch_bounds__(256)
void sinkhorn_kernel(const float* __restrict__ sim, float* out) {
    __shared__ float fv[64], gv[64], redM[4], redA[4], redB[4];
    const int tid  = threadIdx.x;
    const int sr   = tid >> 2;     // row (f-phase) / col (g-phase) handled
    const int q    = tid & 3;
    const int tb   = q * 16;
    const int lane = tid & 63;
    const int wid  = tid >> 6;

    float Mr[16], Mtc[16], Sr[16];
    float mxall = -1e30f;
#pragma unroll
    for (int r = 0; r < 16; ++r) {
        float sv = sim[sr * 64 + tb + r];
        float m  = out[2 + sr * 64 + tb + r] + 0.1f * sv;
        Mr[r] = m; Sr[r] = sv;
        mxall = fmaxf(mxall, m);
        Mtc[r] = out[2 + (tb + r) * 64 + sr] + 0.1f * sim[(tb + r) * 64 + sr];
    }
#pragma unroll
    for (int o = 32; o; o >>= 1) mxall = fmaxf(mxall, __shfl_xor(mxall, o));
    if (lane == 0) redM[wid] = mxall;
    if (tid < 64) { fv[tid] = 0.f; gv[tid] = 0.f; }
    __syncthreads();

    const float maxM = fmaxf(fmaxf(redM[0], redM[1]), fmaxf(redM[2], redM[3]));
    const float eps  = 0.02f * maxM;
    const float ilog = 1.4426950408889634f / eps;        // 1/(eps*ln2)
    const float ceps = 0.69314718055994531f * eps;       // eps*ln2
    const float EL   = eps * (-4.1588830833596715f);     // eps*log(1/64)

    for (int it = 0; it < 300; ++it) {
        // f-phase: rows of M
        {
            float ga[16];
            *(float4*)(ga + 0)  = *(const float4*)(gv + tb + 0);
            *(float4*)(ga + 4)  = *(const float4*)(gv + tb + 4);
            *(float4*)(ga + 8)  = *(const float4*)(gv + tb + 8);
            *(float4*)(ga + 12) = *(const float4*)(gv + tb + 12);
            float mx = -1e30f;
#pragma unroll
            for (int r = 0; r < 16; ++r) { ga[r] = (ga[r] - Mr[r]) * ilog; mx = fmaxf(mx, ga[r]); }
            mx = fmaxf(mx, __shfl_xor(mx, 1));
            mx = fmaxf(mx, __shfl_xor(mx, 2));
            float sum = 0.f;
#pragma unroll
            for (int r = 0; r < 16; ++r) sum += exp2f(ga[r] - mx);
            sum += __shfl_xor(sum, 1);
            sum += __shfl_xor(sum, 2);
            if (q == 0) fv[sr] = EL - ceps * (log2f(sum) + mx);
        }
        __syncthreads();
        // g-phase: cols of M (uses new f)
        {
            float fa[16];
            *(float4*)(fa + 0)  = *(const float4*)(fv + tb + 0);
            *(float4*)(fa + 4)  = *(const float4*)(fv + tb + 4);
            *(float4*)(fa + 8)  = *(const float4*)(fv + tb + 8);
            *(float4*)(fa + 12) = *(const float4*)(fv + tb + 12);
            float mx = -1e30f;
#pragma unroll
            for (int r = 0; r < 16; ++r) { fa[r] = (fa[r] - Mtc[r]) * ilog; mx = fmaxf(mx, fa[r]); }
            mx = fmaxf(mx, __shfl_xor(mx, 1));
            mx = fmaxf(mx, __shfl_xor(mx, 2));
            float sum = 0.f;
#pragma unroll
            for (int r = 0; r < 16; ++r) sum += exp2f(fa[r] - mx);
            sum += __shfl_xor(sum, 1);
            sum += __shfl_xor(sum, 2);
            if (q == 0) gv[sr] = EL - ceps * (log2f(sum) + mx);
        }
        __syncthreads();
    }

    // gamma + final reductions (alpha from dtw = M - 0.1*sim, exact)
    float la = 0.f, lb = 0.f;
    float fs = fv[sr];
#pragma unroll
    for (int r = 0; r < 16; ++r) {
        float gamma = exp2f((fs + gv[tb + r] - Mr[r]) * ilog);
        out[2 + sr * 64 + tb + r] = gamma;
        la = fmaf(gamma, Mr[r] - 0.1f * Sr[r], la);
        lb = fmaf(gamma, Sr[r], lb);
    }
#pragma unroll
    for (int o = 32; o; o >>= 1) { la += __shfl_xor(la, o); lb += __shfl_xor(lb, o); }
    if (lane == 0) { redA[wid] = la; redB[wid] = lb; }
    __syncthreads();
    if (tid == 0) {
        float A  = redA[0] + redA[1] + redA[2] + redA[3];
        float Bc = redB[0] + redB[1] + redB[2] + redB[3];
        out[0] = A * (1.0f / 64.0f);         // length = (64+64)/2 = 64
        out[1] = 0.1f * Bc * (1.0f / 64.0f);
    }
}

extern "C" void kernel_launch(void* const* d_in, const int* in_sizes, int n_in,
                              void* d_out, int out_size, void* d_ws, size_t ws_size,
                              hipStream_t stream) {
    const float* xs  = (const float*)d_in[0];   // (64,128,64) f32
    const float* xt  = (const float*)d_in[1];   // (64,128,64) f32
    const float* sim = (const float*)d_in[3];   // (64,64) f32
    float* out = (float*)d_out;                 // [alpha, beta, gamma(4096)]
    (void)d_ws; (void)ws_size;

    // LDS: 4 pairs * CPAIR bf16 (129 KB) + x2(512B) + y2(2KB) = 131.5 KB
    const int smem = 4 * CPAIR * 2 + (128 + 512) * (int)sizeof(float);
    hipFuncSetAttribute((const void*)fused_dtw_kernel,
                        hipFuncAttributeMaxDynamicSharedMemorySize, smem);

    hipLaunchKernelGGL(fused_dtw_kernel, dim3(1024), dim3(256), smem, stream,
                       xs, xt, out + 2);
    hipLaunchKernelGGL(sinkhorn_kernel, dim3(1), dim3(256), 0, stream,
                       sim, out);
}

// Round 5
// 593.943 us; speedup vs baseline: 2.1465x; 1.3636x over previous
//
#include <hip/hip_runtime.h>
#include <math.h>

#define CPAIR 16512   // compact-diagonal bf16 elems per pair

using bf16x8 = __attribute__((ext_vector_type(8))) short;
using f32x4  = __attribute__((ext_vector_type(4))) float;

// f32 -> bf16 bits, round-to-nearest-even (finite inputs only)
__device__ __forceinline__ unsigned short f2bf(float f) {
    unsigned u = __float_as_uint(f);
    u += 0x7FFFu + ((u >> 16) & 1u);
    return (unsigned short)(u >> 16);
}

__device__ __forceinline__ bf16x8 load_frag(const float* p) {
    float4 u = *(const float4*)p;
    float4 v = *(const float4*)(p + 4);
    bf16x8 f;
    f[0] = (short)f2bf(u.x); f[1] = (short)f2bf(u.y);
    f[2] = (short)f2bf(u.z); f[3] = (short)f2bf(u.w);
    f[4] = (short)f2bf(v.x); f[5] = (short)f2bf(v.y);
    f[6] = (short)f2bf(v.z); f[7] = (short)f2bf(v.w);
    return f;
}

// ---------------------------------------------------------------------------
// 2048 blocks x 128 threads: block b -> s = b>>5, wave w owns t = (b&31)*2+w.
// LDS 68.6 KB -> 2 blocks/CU (GEMM of one block overlaps DP of the other).
//  Phase 0: ideTab (compact-diag row offsets) + squared norms.
//  Phase 1 (per wave): whole XT held in 64 VGPRs (converted once);
//           8x8 MFMA tiles -> C = sqrt(max(d2,1e-12)) bf16 compact-diag LDS.
//  Phase 2 (per wave): DTW anti-diagonal DP, lane l owns cols 2l,2l+1;
//           C reads software-pipelined 2 diagonals ahead.
//           dtw = min(acc[126][126], acc[126][127], acc[127][126]).
// ---------------------------------------------------------------------------
__global__ __launch_bounds__(128, 1)
void fused_dtw_kernel(const float* __restrict__ xs, const float* __restrict__ xt,
                      float* __restrict__ dtw_out) {
    extern __shared__ char smraw[];
    unsigned short* Cd = (unsigned short*)smraw;            // 2 * CPAIR bf16
    float* x2 = (float*)(smraw + 2 * CPAIR * 2);            // [128]
    float* y2 = x2 + 128;                                   // [2*128]
    int* ideTab = (int*)(y2 + 256);                         // [255]

    const int b   = blockIdx.x;
    const int s   = b >> 5;
    const int t0  = (b & 31) * 2;
    const int tid = threadIdx.x;
    const int w    = tid >> 6;
    const int lane = tid & 63;

    const float* XS = xs + (size_t)s * 128 * 64;

    // ---- Phase 0a: ideTab[d] = poff(d) - js + (js&1);  cidx(d,j) = ideTab[d]+j
    for (int d = tid; d < 255; d += 128) {
        int off  = (d <= 128) ? ((d * (d + 1)) >> 1)
                              : (8256 + 127 * (d - 128) - (((d - 128) * (d - 129)) >> 1));
        int poff = off + ((d + 1) >> 1);
        int js   = d - 127; if (js < 0) js = 0;
        ideTab[d] = poff - js + (js & 1);
    }
    // ---- Phase 0b: squared norms (XS 128 rows + 2x128 XT rows)
    for (int e = tid; e < 384; e += 128) {
        const float* src = (e < 128)
            ? (XS + e * 64)
            : (xt + (size_t)(t0 + ((e - 128) >> 7)) * 128 * 64 + ((e - 128) & 127) * 64);
        float a = 0.f;
        const float4* pp = (const float4*)src;
#pragma unroll
        for (int kk = 0; kk < 16; ++kk) {
            float4 vv = pp[kk];
            a = fmaf(vv.x, vv.x, a); a = fmaf(vv.y, vv.y, a);
            a = fmaf(vv.z, vv.z, a); a = fmaf(vv.w, vv.w, a);
        }
        if (e < 128) x2[e] = a; else y2[e - 128] = a;
    }
    __syncthreads();

    // ---- Phase 1: GEMM with XT resident in registers
    const float* XT = xt + (size_t)(t0 + w) * 128 * 64;
    unsigned short* Cw = Cd + w * CPAIR;
    const int r16 = lane & 15;   // A-row / B-col within 16-tile
    const int kq  = lane >> 4;   // k-quad

    bf16x8 Bf[8][2];
#pragma unroll
    for (int j = 0; j < 8; ++j)
#pragma unroll
        for (int kh = 0; kh < 2; ++kh)
            Bf[j][kh] = load_frag(XT + (j * 16 + r16) * 64 + kh * 32 + kq * 8);

    for (int i0 = 0; i0 < 128; i0 += 16) {
        bf16x8 Af0 = load_frag(XS + (i0 + r16) * 64 + kq * 8);
        bf16x8 Af1 = load_frag(XS + (i0 + r16) * 64 + 32 + kq * 8);
        float xr[4];
#pragma unroll
        for (int r = 0; r < 4; ++r) xr[r] = x2[i0 + kq * 4 + r];
        const int ib = i0 + kq * 4;

#pragma unroll
        for (int j = 0; j < 8; ++j) {
            f32x4 acc = {0.f, 0.f, 0.f, 0.f};
            acc = __builtin_amdgcn_mfma_f32_16x16x32_bf16(Af0, Bf[j][0], acc, 0, 0, 0);
            acc = __builtin_amdgcn_mfma_f32_16x16x32_bf16(Af1, Bf[j][1], acc, 0, 0, 0);
            const int jj = j * 16 + r16;
            const float yc = y2[w * 128 + jj];
#pragma unroll
            for (int r = 0; r < 4; ++r) {
                float d2 = xr[r] + yc - 2.f * acc[r];
                float c  = sqrtf(fmaxf(d2, 1e-12f));
                int   dd = ib + r + jj;
                Cw[ideTab[dd] + jj] = f2bf(c);
            }
        }
    }
    // no barrier: each wave's DP reads only its own Cw (same-wave LDS ordering)

    // ---- Phase 2: DP (lane l owns columns 2l, 2l+1), C reads 2 diags ahead
    {
        const int l = lane;
        const float INF = __builtin_inff();
        float c00;
        { unsigned cw0 = *(const unsigned*)Cw; c00 = __uint_as_float(cw0 << 16); }
        float eB   = (l == 0) ? c00 : INF;   // even acc, diag d-1
        float oB   = INF;                    // odd  acc, diag d-1
        float eA   = INF;                    // even acc, diag d-2
        float shoA = INF;                    // lane-1 odd acc, diag d-2

        // bases: base(1)=2, base(2)=4; step(x->x+1): x<=127 ? x+1+!(x&1) : 254-x+(x&1)
        int bLast = 4;
        unsigned cw1 = *(const unsigned*)(Cw + 2 + 2 * l);      // C(d=1)
        unsigned cw2 = *(const unsigned*)(Cw + 4 + 2 * l);      // C(d=2)
        int ie = 1 - 2 * l;

        for (int d = 1; d <= 253; ++d) {
            int dn = d + 1;
            int bn = bLast + ((dn <= 127) ? (dn + 1 + !(dn & 1)) : (254 - dn + (dn & 1)));
            unsigned cwN = *(const unsigned*)(Cw + bn + 2 * l);  // C(d+2), in-bounds thru d=253

            float shoB = __shfl_up(oB, 1);
            if (l == 0) shoB = INF;
            float c_e = __uint_as_float(cw1 << 16);
            float c_o = __uint_as_float(cw1 & 0xFFFF0000u);
            float ne = (ie >= 0 && ie <= 127) ? c_e + fminf(shoA, fminf(eB, shoB)) : INF;
            float no = (ie >= 1 && ie <= 128) ? c_o + fminf(eA, fminf(oB, eB))     : INF;

            eA = eB; eB = ne; oB = no; shoA = shoB;
            cw1 = cw2; cw2 = cwN; bLast = bn; ++ie;
        }
        // eA=(126,126), eB=(127,126), oB=(126,127)
        if (l == 63) dtw_out[s * 64 + t0 + w] = fminf(fminf(eA, eB), oB);
    }
}

// ---------------------------------------------------------------------------
// Sinkhorn v3: incremental log2-domain update, no max-stabilization.
//   F <- F - 6 - log2( sum_t exp2(F + G_t - M*ilog) )   (ceps*ilog == 1;
//   6 = -log2(1/64)).  Identical fixed-point math to the reference
//   (lse(x+c)=lse(x)+c); all exponents <= 0 (<= -6 after first half-iter),
//   so exp2 cannot overflow and stabilization is unnecessary.
// 256 threads, row/col sr per 4-lane group; 4-acc sum breaks the serial chain.
// ---------------------------------------------------------------------------
__global__ __launch_bounds__(256, 1)
void sinkhorn_kernel(const float* __restrict__ sim, float* out) {
    __shared__ float fv[64], gv[64], redM[4], redA[4], redB[4];
    const int tid  = threadIdx.x;
    const int sr   = tid >> 2;
    const int q    = tid & 3;
    const int tb   = q * 16;
    const int lane = tid & 63;
    const int wid  = tid >> 6;

    float Mr[16], Sr[16], Mcs[16];
    float mx = -1e30f;
#pragma unroll
    for (int r = 0; r < 16; ++r) {
        float sv = sim[sr * 64 + tb + r];
        float m  = out[2 + sr * 64 + tb + r] + 0.1f * sv;   // cost_OT row slice
        Mr[r] = m; Sr[r] = sv;
        mx = fmaxf(mx, m);
        Mcs[r] = out[2 + (tb + r) * 64 + sr] + 0.1f * sim[(tb + r) * 64 + sr];
    }
#pragma unroll
    for (int o = 32; o; o >>= 1) mx = fmaxf(mx, __shfl_xor(mx, o));
    if (lane == 0) redM[wid] = mx;
    if (tid < 64) { fv[tid] = 0.f; gv[tid] = 0.f; }
    __syncthreads();

    const float maxM = fmaxf(fmaxf(redM[0], redM[1]), fmaxf(redM[2], redM[3]));
    const float eps  = 0.02f * maxM;
    const float ilog = 1.4426950408889634f / eps;   // log2(e)/eps

    float Mrs[16];
#pragma unroll
    for (int r = 0; r < 16; ++r) { Mrs[r] = Mr[r] * ilog; Mcs[r] = Mcs[r] * ilog; }

    float F = 0.f, G = 0.f;   // log2-scaled potentials for row sr / col sr

    for (int it = 0; it < 300; ++it) {
        {   // f-phase (rows)
            float ga[16];
            *(float4*)(ga + 0)  = *(const float4*)(gv + tb + 0);
            *(float4*)(ga + 4)  = *(const float4*)(gv + tb + 4);
            *(float4*)(ga + 8)  = *(const float4*)(gv + tb + 8);
            *(float4*)(ga + 12) = *(const float4*)(gv + tb + 12);
            float s0 = 0.f, s1 = 0.f, s2 = 0.f, s3 = 0.f;
#pragma unroll
            for (int r = 0; r < 16; r += 4) {
                s0 += exp2f(F + ga[r + 0] - Mrs[r + 0]);
                s1 += exp2f(F + ga[r + 1] - Mrs[r + 1]);
                s2 += exp2f(F + ga[r + 2] - Mrs[r + 2]);
                s3 += exp2f(F + ga[r + 3] - Mrs[r + 3]);
            }
            float sum = (s0 + s1) + (s2 + s3);
            sum += __shfl_xor(sum, 1);
            sum += __shfl_xor(sum, 2);
            F = F - 6.0f - log2f(sum);
            if (q == 0) fv[sr] = F;
        }
        __syncthreads();
        {   // g-phase (cols, uses new f)
            float fa[16];
            *(float4*)(fa + 0)  = *(const float4*)(fv + tb + 0);
            *(float4*)(fa + 4)  = *(const float4*)(fv + tb + 4);
            *(float4*)(fa + 8)  = *(const float4*)(fv + tb + 8);
            *(float4*)(fa + 12) = *(const float4*)(fv + tb + 12);
            float s0 = 0.f, s1 = 0.f, s2 = 0.f, s3 = 0.f;
#pragma unroll
            for (int r = 0; r < 16; r += 4) {
                s0 += exp2f(G + fa[r + 0] - Mcs[r + 0]);
                s1 += exp2f(G + fa[r + 1] - Mcs[r + 1]);
                s2 += exp2f(G + fa[r + 2] - Mcs[r + 2]);
                s3 += exp2f(G + fa[r + 3] - Mcs[r + 3]);
            }
            float sum = (s0 + s1) + (s2 + s3);
            sum += __shfl_xor(sum, 1);
            sum += __shfl_xor(sum, 2);
            G = G - 6.0f - log2f(sum);
            if (q == 0) gv[sr] = G;
        }
        __syncthreads();
    }

    // gamma + final reductions (dtw = M - 0.1*sim, exact reconstruction)
    float la = 0.f, lb = 0.f;
    float ga[16];
    *(float4*)(ga + 0)  = *(const float4*)(gv + tb + 0);
    *(float4*)(ga + 4)  = *(const float4*)(gv + tb + 4);
    *(float4*)(ga + 8)  = *(const float4*)(gv + tb + 8);
    *(float4*)(ga + 12) = *(const float4*)(gv + tb + 12);
#pragma unroll
    for (int r = 0; r < 16; ++r) {
        float gamma = exp2f(F + ga[r] - Mrs[r]);
        out[2 + sr * 64 + tb + r] = gamma;
        la = fmaf(gamma, Mr[r] - 0.1f * Sr[r], la);
        lb = fmaf(gamma, Sr[r], lb);
    }
#pragma unroll
    for (int o = 32; o; o >>= 1) { la += __shfl_xor(la, o); lb += __shfl_xor(lb, o); }
    if (lane == 0) { redA[wid] = la; redB[wid] = lb; }
    __syncthreads();
    if (tid == 0) {
        float A  = redA[0] + redA[1] + redA[2] + redA[3];
        float Bc = redB[0] + redB[1] + redB[2] + redB[3];
        out[0] = A * (1.0f / 64.0f);          // length = (64+64)/2 = 64
        out[1] = 0.1f * Bc * (1.0f / 64.0f);
    }
}

extern "C" void kernel_launch(void* const* d_in, const int* in_sizes, int n_in,
                              void* d_out, int out_size, void* d_ws, size_t ws_size,
                              hipStream_t stream) {
    const float* xs  = (const float*)d_in[0];   // (64,128,64) f32
    const float* xt  = (const float*)d_in[1];   // (64,128,64) f32
    const float* sim = (const float*)d_in[3];   // (64,64) f32
    float* out = (float*)d_out;                 // [alpha, beta, gamma(4096)]
    (void)d_ws; (void)ws_size;

    // LDS: 2*CPAIR bf16 (64.5K) + x2(512B) + y2(1K) + ideTab(1020B) = 68.6 KB
    const int smem = 2 * CPAIR * 2 + (128 + 256) * (int)sizeof(float) + 255 * (int)sizeof(int);
    hipFuncSetAttribute((const void*)fused_dtw_kernel,
                        hipFuncAttributeMaxDynamicSharedMemorySize, smem);

    hipLaunchKernelGGL(fused_dtw_kernel, dim3(2048), dim3(128), smem, stream,
                       xs, xt, out + 2);
    hipLaunchKernelGGL(sinkhorn_kernel, dim3(1), dim3(256), 0, stream,
                       sim, out);
}

// Round 10
// 505.378 us; speedup vs baseline: 2.5227x; 1.1752x over previous
//
#include <hip/hip_runtime.h>
#include <math.h>

#define CROW 132            // C row stride in shorts (128 + 4 pad: bank-spreads GEMM stores)
#define CPAIR (128 * CROW)  // 16896 shorts = 33792 B per pair

using bf16x8 = __attribute__((ext_vector_type(8))) short;
using f32x4  = __attribute__((ext_vector_type(4))) float;

// f32 -> bf16 bits, round-to-nearest-even (finite inputs only)
__device__ __forceinline__ unsigned short f2bf(float f) {
    unsigned u = __float_as_uint(f);
    u += 0x7FFFu + ((u >> 16) & 1u);
    return (unsigned short)(u >> 16);
}

__device__ __forceinline__ bf16x8 load_frag(const float* p) {
    float4 u = *(const float4*)p;
    float4 v = *(const float4*)(p + 4);
    bf16x8 f;
    f[0] = (short)f2bf(u.x); f[1] = (short)f2bf(u.y);
    f[2] = (short)f2bf(u.z); f[3] = (short)f2bf(u.w);
    f[4] = (short)f2bf(v.x); f[5] = (short)f2bf(v.y);
    f[6] = (short)f2bf(v.z); f[7] = (short)f2bf(v.w);
    return f;
}

// Wave-wide lane l-1 -> lane l shift. row_shr:1 covers intra-row; row_bcast15
// (lane15->row1, lane31->row2, lane47->row3) supplies the row boundaries;
// `patch` (loop-invariant: l==16/32/48) selects.  Lane 0 gets `fill`.
// ~3 VALU ops, no LDS — replaces ds_bpermute (~120cyc) on the DP serial chain.
__device__ __forceinline__ float shift_up1(float x, float fill, bool patch) {
    int xi = __float_as_int(x);
    int fi = __float_as_int(fill);
    int sh = __builtin_amdgcn_update_dpp(fi, xi, 0x111 /*row_shr:1*/, 0xF, 0xF, false);
    int bc = __builtin_amdgcn_update_dpp(fi, xi, 0x142 /*row_bcast15*/, 0xF, 0xF, false);
    return __int_as_float(patch ? bc : sh);
}

// ---------------------------------------------------------------------------
// 2048 blocks x 128 threads: block b -> s = b>>5, wave w owns t = (b&31)*2+w.
// LDS 69.1 KB -> 2 blocks/CU.
//  Phase 0: squared norms.
//  Phase 1 (per wave): XT in 64 VGPRs; MFMA 16x16x32 -> C row-major bf16
//           [128][CROW] in LDS (stores: uniform 2-way across banks = free).
//  Phase 2 (per wave): skewed-band DTW DP: lane l owns cols 2l,2l+1 and
//           computes row i at step tau = i + l (191 steps).  Left/diag
//           neighbors via DPP shift; C reads prefetched 4 diagonals ahead.
//           dtw = min(acc[126][126], acc[126][127], acc[127][126]).
// ---------------------------------------------------------------------------
__global__ __launch_bounds__(128, 1)
void fused_dtw_kernel(const float* __restrict__ xs, const float* __restrict__ xt,
                      float* __restrict__ dtw_out) {
    extern __shared__ char smraw[];
    unsigned short* Cd = (unsigned short*)smraw;          // 2 * CPAIR shorts
    float* x2 = (float*)(smraw + 2 * CPAIR * 2);          // [128]
    float* y2 = x2 + 128;                                 // [2*128]

    const int b   = blockIdx.x;
    const int s   = b >> 5;
    const int t0  = (b & 31) * 2;
    const int tid = threadIdx.x;
    const int w    = tid >> 6;
    const int lane = tid & 63;

    const float* XS = xs + (size_t)s * 128 * 64;

    // ---- Phase 0: squared norms (XS 128 rows + 2x128 XT rows)
    for (int e = tid; e < 384; e += 128) {
        const float* src = (e < 128)
            ? (XS + e * 64)
            : (xt + (size_t)(t0 + ((e - 128) >> 7)) * 128 * 64 + ((e - 128) & 127) * 64);
        float a = 0.f;
        const float4* pp = (const float4*)src;
#pragma unroll
        for (int kk = 0; kk < 16; ++kk) {
            float4 vv = pp[kk];
            a = fmaf(vv.x, vv.x, a); a = fmaf(vv.y, vv.y, a);
            a = fmaf(vv.z, vv.z, a); a = fmaf(vv.w, vv.w, a);
        }
        if (e < 128) x2[e] = a; else y2[e - 128] = a;
    }
    __syncthreads();

    // ---- Phase 1: GEMM with XT resident in registers
    const float* XT = xt + (size_t)(t0 + w) * 128 * 64;
    unsigned short* Cw = Cd + w * CPAIR;
    const int r16 = lane & 15;   // A-row / B-col within 16-tile
    const int kq  = lane >> 4;   // k-quad

    bf16x8 Bf[8][2];
#pragma unroll
    for (int j = 0; j < 8; ++j)
#pragma unroll
        for (int kh = 0; kh < 2; ++kh)
            Bf[j][kh] = load_frag(XT + (j * 16 + r16) * 64 + kh * 32 + kq * 8);

    for (int i0 = 0; i0 < 128; i0 += 16) {
        bf16x8 Af0 = load_frag(XS + (i0 + r16) * 64 + kq * 8);
        bf16x8 Af1 = load_frag(XS + (i0 + r16) * 64 + 32 + kq * 8);
        float xr[4];
#pragma unroll
        for (int r = 0; r < 4; ++r) xr[r] = x2[i0 + kq * 4 + r];
        const int ib = i0 + kq * 4;

#pragma unroll
        for (int j = 0; j < 8; ++j) {
            f32x4 acc = {0.f, 0.f, 0.f, 0.f};
            acc = __builtin_amdgcn_mfma_f32_16x16x32_bf16(Af0, Bf[j][0], acc, 0, 0, 0);
            acc = __builtin_amdgcn_mfma_f32_16x16x32_bf16(Af1, Bf[j][1], acc, 0, 0, 0);
            const int jj = j * 16 + r16;
            const float yc = y2[w * 128 + jj];
#pragma unroll
            for (int r = 0; r < 4; ++r) {
                float d2 = xr[r] + yc - 2.f * acc[r];
                float c  = sqrtf(fmaxf(d2, 1e-12f));
                Cw[(ib + r) * CROW + jj] = f2bf(c);
            }
        }
    }
    // no barrier: each wave's DP reads only its own Cw (same-wave LDS ordering)

    // ---- Phase 2: skewed-band DP.  tau = i + lane; 191 steps.
    {
        const int l = lane;
        const float INF = __builtin_inff();
        const bool patch = (l == 16) || (l == 32) || (l == 48);

        // clamped C read for step tau: row i = tau - l, cols 2l, 2l+1 (one u32)
        auto rd = [&](int tau) -> unsigned {
            int i = tau - l;
            i = i < 0 ? 0 : (i > 127 ? 127 : i);
            return *(const unsigned*)(Cw + i * CROW + 2 * l);
        };

        unsigned cwA = rd(0), cwB = rd(1), cwC = rd(2), cwD = rd(3);
        float eU = INF;                      // own acc[i-1][2l]
        float oU = INF;                      // own acc[i-1][2l+1]
        float shD = (l == 0) ? 0.f : INF;    // acc[i-1][2l-1]; l==0: virtual origin
        float sE = INF, sO = INF;

#define DP_STEP(TAU)                                                        \
        {                                                                   \
            unsigned cwN = rd((TAU) + 4);                                   \
            float shL = shift_up1(oU, INF, patch);   /* acc[i][2l-1] */     \
            float c_e = __uint_as_float(cwA << 16);                         \
            float c_o = __uint_as_float(cwA & 0xFFFF0000u);                 \
            int   i   = (TAU) - l;                                          \
            float ev  = c_e + fminf(shD, fminf(eU, shL));                   \
            float od  = c_o + fminf(eU, fminf(oU, ev));                     \
            bool  valid = (i >= 0) && (i <= 127);                           \
            ev = valid ? ev : INF;                                          \
            od = valid ? od : INF;                                          \
            shD = shL; eU = ev; oU = od;                                    \
            cwA = cwB; cwB = cwC; cwC = cwD; cwD = cwN;                     \
        }

        for (int tau = 0; tau <= 189; ++tau) DP_STEP(tau);
        sE = eU; sO = oU;                    // lane 63: acc[126][126], acc[126][127]
        DP_STEP(190);                        // lane 63: eU = acc[127][126]
#undef DP_STEP

        if (l == 63) dtw_out[s * 64 + t0 + w] = fminf(fminf(sE, sO), eU);
    }
}

// ---------------------------------------------------------------------------
// Sinkhorn v4: single wave (64 lanes), zero barriers, linear-domain matvec.
//   K = exp2(-M*ilog) precomputed in VGPRs (row + col per lane).
//   F_s = -6 - log2( sum_t K_st * exp2(G_t) )   [F cancels: lse(F+x)=F+lse(x)]
//   G_t = -6 - log2( sum_s K_st * exp2(F_s) )
//   u-broadcast via v_readlane (imm lane) -> SGPR operand folds into the fma.
//   gamma = exp2(F)*exp2(G)*K.  Identical fixed point to the reference
//   log-domain scan; f32-safe (M*ilog <= 72.2 -> K >= 2^-73).
// Reads dtw from out[2..]; overwrites with gamma at the end (per-lane rows).
// ---------------------------------------------------------------------------
__device__ __forceinline__ float rlane(float x, int t) {
    return __int_as_float(__builtin_amdgcn_readlane(__float_as_int(x), t));
}

__global__ __launch_bounds__(64, 1)
void sinkhorn_kernel(const float* __restrict__ sim, float* out) {
    const int l = threadIdx.x;   // row s = l (f-phase), col t = l (g-phase)

    // row of M = dtw + 0.1*sim; global max via row maxes
    float Mrow[64];
    float mx = -1e30f;
#pragma unroll
    for (int r = 0; r < 64; ++r) {
        Mrow[r] = out[2 + l * 64 + r] + 0.1f * sim[l * 64 + r];
        mx = fmaxf(mx, Mrow[r]);
    }
#pragma unroll
    for (int o = 32; o; o >>= 1) mx = fmaxf(mx, __shfl_xor(mx, o));

    const float eps  = 0.02f * mx;
    const float ilog = 1.4426950408889634f / eps;   // log2(e)/eps

    float Kr[64];
#pragma unroll
    for (int r = 0; r < 64; ++r) Kr[r] = exp2f(-Mrow[r] * ilog);   // Mrow dies here

    float Kc[64];
#pragma unroll
    for (int r = 0; r < 64; ++r) {
        float mc = out[2 + r * 64 + l] + 0.1f * sim[r * 64 + l];
        Kc[r] = exp2f(-mc * ilog);
    }

    float F = 0.f, G = 0.f;
    for (int it = 0; it < 300; ++it) {
        {   // f-phase
            float ug = exp2f(G);
            float s0 = 0.f, s1 = 0.f, s2 = 0.f, s3 = 0.f;
#pragma unroll
            for (int t = 0; t < 64; t += 4) {
                s0 = fmaf(Kr[t + 0], rlane(ug, t + 0), s0);
                s1 = fmaf(Kr[t + 1], rlane(ug, t + 1), s1);
                s2 = fmaf(Kr[t + 2], rlane(ug, t + 2), s2);
                s3 = fmaf(Kr[t + 3], rlane(ug, t + 3), s3);
            }
            F = -6.0f - log2f((s0 + s1) + (s2 + s3));
        }
        {   // g-phase (uses new F)
            float uf = exp2f(F);
            float s0 = 0.f, s1 = 0.f, s2 = 0.f, s3 = 0.f;
#pragma unroll
            for (int t = 0; t < 64; t += 4) {
                s0 = fmaf(Kc[t + 0], rlane(uf, t + 0), s0);
                s1 = fmaf(Kc[t + 1], rlane(uf, t + 1), s1);
                s2 = fmaf(Kc[t + 2], rlane(uf, t + 2), s2);
                s3 = fmaf(Kc[t + 3], rlane(uf, t + 3), s3);
            }
            G = -6.0f - log2f((s0 + s1) + (s2 + s3));
        }
    }

    // epilogue: gamma row l = uf * ug_t * Kr[t]; alpha/beta reductions.
    // dtw row re-read BEFORE overwrite (per-lane exclusive row ownership).
    const float uf = exp2f(F);
    const float ug_own = exp2f(G);
    float la = 0.f, lb = 0.f;
#pragma unroll
    for (int t = 0; t < 64; ++t) {
        float dt = out[2 + l * 64 + t];          // dtw (still unmodified for this row)
        float sv = sim[l * 64 + t];
        float ga = uf * Kr[t] * rlane(ug_own, t);
        out[2 + l * 64 + t] = ga;
        la = fmaf(ga, dt, la);
        lb = fmaf(ga, sv, lb);
    }
#pragma unroll
    for (int o = 32; o; o >>= 1) { la += __shfl_xor(la, o); lb += __shfl_xor(lb, o); }
    if (l == 0) {
        out[0] = la * (1.0f / 64.0f);            // length = (64+64)/2 = 64
        out[1] = 0.1f * lb * (1.0f / 64.0f);
    }
}

extern "C" void kernel_launch(void* const* d_in, const int* in_sizes, int n_in,
                              void* d_out, int out_size, void* d_ws, size_t ws_size,
                              hipStream_t stream) {
    const float* xs  = (const float*)d_in[0];   // (64,128,64) f32
    const float* xt  = (const float*)d_in[1];   // (64,128,64) f32
    const float* sim = (const float*)d_in[3];   // (64,64) f32
    float* out = (float*)d_out;                 // [alpha, beta, gamma(4096)]
    (void)d_ws; (void)ws_size;

    // LDS: 2*CPAIR shorts (67.6K) + x2(512B) + y2(1K) = 69.1 KB -> 2 blocks/CU
    const int smem = 2 * CPAIR * 2 + (128 + 256) * (int)sizeof(float);
    (void)hipFuncSetAttribute((const void*)fused_dtw_kernel,
                              hipFuncAttributeMaxDynamicSharedMemorySize, smem);

    hipLaunchKernelGGL(fused_dtw_kernel, dim3(2048), dim3(128), smem, stream,
                       xs, xt, out + 2);
    hipLaunchKernelGGL(sinkhorn_kernel, dim3(1), dim3(64), 0, stream,
                       sim, out);
}

// Round 12
// 377.957 us; speedup vs baseline: 3.3732x; 1.3371x over previous
//
#include <hip/hip_runtime.h>
#include <math.h>

#define CROW 132            // C row stride in shorts (128 + 4 pad: bank-spreads GEMM stores)
#define CPAIR (128 * CROW)  // 16896 shorts = 33792 B per pair

using bf16x8 = __attribute__((ext_vector_type(8))) short;
using f32x4  = __attribute__((ext_vector_type(4))) float;

// f32 -> bf16 bits, round-to-nearest-even (finite inputs only)
__device__ __forceinline__ unsigned short f2bf(float f) {
    unsigned u = __float_as_uint(f);
    u += 0x7FFFu + ((u >> 16) & 1u);
    return (unsigned short)(u >> 16);
}

__device__ __forceinline__ bf16x8 load_frag(const float* p) {
    float4 u = *(const float4*)p;
    float4 v = *(const float4*)(p + 4);
    bf16x8 f;
    f[0] = (short)f2bf(u.x); f[1] = (short)f2bf(u.y);
    f[2] = (short)f2bf(u.z); f[3] = (short)f2bf(u.w);
    f[4] = (short)f2bf(v.x); f[5] = (short)f2bf(v.y);
    f[6] = (short)f2bf(v.z); f[7] = (short)f2bf(v.w);
    return f;
}

// Wave-wide lane l-1 -> lane l shift. row_shr:1 covers intra-row; row_bcast15
// (lane15->row1, lane31->row2, lane47->row3) supplies the row boundaries;
// `patch` (loop-invariant: l==16/32/48) selects.  Lane 0 gets `fill`.
__device__ __forceinline__ float shift_up1(float x, float fill, bool patch) {
    int xi = __float_as_int(x);
    int fi = __float_as_int(fill);
    int sh = __builtin_amdgcn_update_dpp(fi, xi, 0x111 /*row_shr:1*/, 0xF, 0xF, false);
    int bc = __builtin_amdgcn_update_dpp(fi, xi, 0x142 /*row_bcast15*/, 0xF, 0xF, false);
    return __int_as_float(patch ? bc : sh);
}

// ---------------------------------------------------------------------------
// fused_dtw: unchanged from the measured 213 µs version (round 10).
// ---------------------------------------------------------------------------
__global__ __launch_bounds__(128, 1)
void fused_dtw_kernel(const float* __restrict__ xs, const float* __restrict__ xt,
                      float* __restrict__ dtw_out) {
    extern __shared__ char smraw[];
    unsigned short* Cd = (unsigned short*)smraw;          // 2 * CPAIR shorts
    float* x2 = (float*)(smraw + 2 * CPAIR * 2);          // [128]
    float* y2 = x2 + 128;                                 // [2*128]

    const int b   = blockIdx.x;
    const int s   = b >> 5;
    const int t0  = (b & 31) * 2;
    const int tid = threadIdx.x;
    const int w    = tid >> 6;
    const int lane = tid & 63;

    const float* XS = xs + (size_t)s * 128 * 64;

    // ---- Phase 0: squared norms (XS 128 rows + 2x128 XT rows)
    for (int e = tid; e < 384; e += 128) {
        const float* src = (e < 128)
            ? (XS + e * 64)
            : (xt + (size_t)(t0 + ((e - 128) >> 7)) * 128 * 64 + ((e - 128) & 127) * 64);
        float a = 0.f;
        const float4* pp = (const float4*)src;
#pragma unroll
        for (int kk = 0; kk < 16; ++kk) {
            float4 vv = pp[kk];
            a = fmaf(vv.x, vv.x, a); a = fmaf(vv.y, vv.y, a);
            a = fmaf(vv.z, vv.z, a); a = fmaf(vv.w, vv.w, a);
        }
        if (e < 128) x2[e] = a; else y2[e - 128] = a;
    }
    __syncthreads();

    // ---- Phase 1: GEMM with XT resident in registers
    const float* XT = xt + (size_t)(t0 + w) * 128 * 64;
    unsigned short* Cw = Cd + w * CPAIR;
    const int r16 = lane & 15;   // A-row / B-col within 16-tile
    const int kq  = lane >> 4;   // k-quad

    bf16x8 Bf[8][2];
#pragma unroll
    for (int j = 0; j < 8; ++j)
#pragma unroll
        for (int kh = 0; kh < 2; ++kh)
            Bf[j][kh] = load_frag(XT + (j * 16 + r16) * 64 + kh * 32 + kq * 8);

    for (int i0 = 0; i0 < 128; i0 += 16) {
        bf16x8 Af0 = load_frag(XS + (i0 + r16) * 64 + kq * 8);
        bf16x8 Af1 = load_frag(XS + (i0 + r16) * 64 + 32 + kq * 8);
        float xr[4];
#pragma unroll
        for (int r = 0; r < 4; ++r) xr[r] = x2[i0 + kq * 4 + r];
        const int ib = i0 + kq * 4;

#pragma unroll
        for (int j = 0; j < 8; ++j) {
            f32x4 acc = {0.f, 0.f, 0.f, 0.f};
            acc = __builtin_amdgcn_mfma_f32_16x16x32_bf16(Af0, Bf[j][0], acc, 0, 0, 0);
            acc = __builtin_amdgcn_mfma_f32_16x16x32_bf16(Af1, Bf[j][1], acc, 0, 0, 0);
            const int jj = j * 16 + r16;
            const float yc = y2[w * 128 + jj];
#pragma unroll
            for (int r = 0; r < 4; ++r) {
                float d2 = xr[r] + yc - 2.f * acc[r];
                float c  = sqrtf(fmaxf(d2, 1e-12f));
                Cw[(ib + r) * CROW + jj] = f2bf(c);
            }
        }
    }
    // no barrier: each wave's DP reads only its own Cw (same-wave LDS ordering)

    // ---- Phase 2: skewed-band DP.  tau = i + lane; 191 steps.
    {
        const int l = lane;
        const float INF = __builtin_inff();
        const bool patch = (l == 16) || (l == 32) || (l == 48);

        auto rd = [&](int tau) -> unsigned {
            int i = tau - l;
            i = i < 0 ? 0 : (i > 127 ? 127 : i);
            return *(const unsigned*)(Cw + i * CROW + 2 * l);
        };

        unsigned cwA = rd(0), cwB = rd(1), cwC = rd(2), cwD = rd(3);
        float eU = INF;                      // own acc[i-1][2l]
        float oU = INF;                      // own acc[i-1][2l+1]
        float shD = (l == 0) ? 0.f : INF;    // acc[i-1][2l-1]; l==0: virtual origin
        float sE = INF, sO = INF;

#define DP_STEP(TAU)                                                        \
        {                                                                   \
            unsigned cwN = rd((TAU) + 4);                                   \
            float shL = shift_up1(oU, INF, patch);   /* acc[i][2l-1] */     \
            float c_e = __uint_as_float(cwA << 16);                         \
            float c_o = __uint_as_float(cwA & 0xFFFF0000u);                 \
            int   i   = (TAU) - l;                                          \
            float ev  = c_e + fminf(shD, fminf(eU, shL));                   \
            float od  = c_o + fminf(eU, fminf(oU, ev));                     \
            bool  valid = (i >= 0) && (i <= 127);                           \
            ev = valid ? ev : INF;                                          \
            od = valid ? od : INF;                                          \
            shD = shL; eU = ev; oU = od;                                    \
            cwA = cwB; cwB = cwC; cwC = cwD; cwD = cwN;                     \
        }

        for (int tau = 0; tau <= 189; ++tau) DP_STEP(tau);
        sE = eU; sO = oU;                    // lane 63: acc[126][126], acc[126][127]
        DP_STEP(190);                        // lane 63: eU = acc[127][126]
#undef DP_STEP

        if (l == 63) dtw_out[s * 64 + t0 + w] = fminf(fminf(sE, sO), eU);
    }
}

// ---------------------------------------------------------------------------
// Sinkhorn v5: single wave, K matrices in LDS t-major (defeats the VGPR spill
// that dominated v4: VGPR_Count=84 vs 128+ needed -> scratch reloads every
// phase).  Per-phase: 64 conflict-free ds_read_b32 (banks = l%32, 2-way free)
// + 16 uniform-addr float4 u-broadcast reads + 64 fma in 8 chains.
//   F = -6 - log2( sum_t K[l][t] * exp2(G_t) ),  G analogous (new F).
// Exact bitwise convergence exit: if G unchanged across one iteration, all
// later iterates are bit-identical (deterministic fixed point) -> break.
// ---------------------------------------------------------------------------
__global__ __launch_bounds__(64, 1)
void sinkhorn_kernel(const float* __restrict__ sim, float* out) {
    __shared__ float Krt[64 * 64];                 // Krt[t*64+l] = K[l][t]
    __shared__ float Kct[64 * 64];                 // Kct[r*64+l] = K[r][l]
    __shared__ __align__(16) float ub[64];         // u broadcast buffer
    const int l = threadIdx.x;

    // ---- pass 0: global max of M = dtw + 0.1*sim
    float mx = -1e30f;
#pragma unroll
    for (int q = 0; q < 16; ++q) {
        float4 d4 = *(const float4*)&out[2 + l * 64 + 4 * q];
        float4 s4 = *(const float4*)&sim[l * 64 + 4 * q];
        mx = fmaxf(mx, fmaxf(fmaxf(d4.x + 0.1f * s4.x, d4.y + 0.1f * s4.y),
                             fmaxf(d4.z + 0.1f * s4.z, d4.w + 0.1f * s4.w)));
    }
#pragma unroll
    for (int o = 32; o; o >>= 1) mx = fmaxf(mx, __shfl_xor(mx, o));

    const float eps  = 0.02f * mx;
    const float ilog = 1.4426950408889634f / eps;   // log2(e)/eps

    // ---- pass 1: K matrices into LDS (t-major; 2-way bank access = free)
#pragma unroll 4
    for (int t = 0; t < 64; ++t) {
        float mr = out[2 + l * 64 + t] + 0.1f * sim[l * 64 + t];
        Krt[t * 64 + l] = exp2f(-mr * ilog);
        float mc = out[2 + t * 64 + l] + 0.1f * sim[t * 64 + l];
        Kct[t * 64 + l] = exp2f(-mc * ilog);
    }

    float F = 0.f, G = 0.f;
    for (int it = 0; it < 300; ++it) {
        const float Gold = G;
        {   // f-phase
            ub[l] = exp2f(G);   // DS ops in-order per wave: reads below see this
            float s0 = 0.f, s1 = 0.f, s2 = 0.f, s3 = 0.f,
                  s4 = 0.f, s5 = 0.f, s6 = 0.f, s7 = 0.f;
#pragma unroll
            for (int q = 0; q < 8; ++q) {
                float4 u0 = *(const float4*)&ub[8 * q];
                float4 u1 = *(const float4*)&ub[8 * q + 4];
                s0 = fmaf(Krt[(8 * q + 0) * 64 + l], u0.x, s0);
                s1 = fmaf(Krt[(8 * q + 1) * 64 + l], u0.y, s1);
                s2 = fmaf(Krt[(8 * q + 2) * 64 + l], u0.z, s2);
                s3 = fmaf(Krt[(8 * q + 3) * 64 + l], u0.w, s3);
                s4 = fmaf(Krt[(8 * q + 4) * 64 + l], u1.x, s4);
                s5 = fmaf(Krt[(8 * q + 5) * 64 + l], u1.y, s5);
                s6 = fmaf(Krt[(8 * q + 6) * 64 + l], u1.z, s6);
                s7 = fmaf(Krt[(8 * q + 7) * 64 + l], u1.w, s7);
            }
            F = -6.0f - log2f(((s0 + s1) + (s2 + s3)) + ((s4 + s5) + (s6 + s7)));
        }
        {   // g-phase (uses new F)
            ub[l] = exp2f(F);
            float s0 = 0.f, s1 = 0.f, s2 = 0.f, s3 = 0.f,
                  s4 = 0.f, s5 = 0.f, s6 = 0.f, s7 = 0.f;
#pragma unroll
            for (int q = 0; q < 8; ++q) {
                float4 u0 = *(const float4*)&ub[8 * q];
                float4 u1 = *(const float4*)&ub[8 * q + 4];
                s0 = fmaf(Kct[(8 * q + 0) * 64 + l], u0.x, s0);
                s1 = fmaf(Kct[(8 * q + 1) * 64 + l], u0.y, s1);
                s2 = fmaf(Kct[(8 * q + 2) * 64 + l], u0.z, s2);
                s3 = fmaf(Kct[(8 * q + 3) * 64 + l], u0.w, s3);
                s4 = fmaf(Kct[(8 * q + 4) * 64 + l], u1.x, s4);
                s5 = fmaf(Kct[(8 * q + 5) * 64 + l], u1.y, s5);
                s6 = fmaf(Kct[(8 * q + 6) * 64 + l], u1.z, s6);
                s7 = fmaf(Kct[(8 * q + 7) * 64 + l], u1.w, s7);
            }
            G = -6.0f - log2f(((s0 + s1) + (s2 + s3)) + ((s4 + s5) + (s6 + s7)));
        }
        // exact early exit: G bit-unchanged => all later iterates identical
        if (__all(__float_as_uint(G) == __float_as_uint(Gold))) break;
    }

    // ---- epilogue: gamma = uf * ug_t * K[l][t]; alpha/beta reductions.
    const float uf = exp2f(F);
    ub[l] = exp2f(G);
    float la = 0.f, lb = 0.f;
#pragma unroll 8
    for (int t = 0; t < 64; ++t) {
        float dt = out[2 + l * 64 + t];          // dtw (row l still unmodified)
        float sv = sim[l * 64 + t];
        float ga = uf * Krt[t * 64 + l] * ub[t];
        out[2 + l * 64 + t] = ga;
        la = fmaf(ga, dt, la);
        lb = fmaf(ga, sv, lb);
    }
#pragma unroll
    for (int o = 32; o; o >>= 1) { la += __shfl_xor(la, o); lb += __shfl_xor(lb, o); }
    if (l == 0) {
        out[0] = la * (1.0f / 64.0f);            // length = (64+64)/2 = 64
        out[1] = 0.1f * lb * (1.0f / 64.0f);
    }
}

extern "C" void kernel_launch(void* const* d_in, const int* in_sizes, int n_in,
                              void* d_out, int out_size, void* d_ws, size_t ws_size,
                              hipStream_t stream) {
    const float* xs  = (const float*)d_in[0];   // (64,128,64) f32
    const float* xt  = (const float*)d_in[1];   // (64,128,64) f32
    const float* sim = (const float*)d_in[3];   // (64,64) f32
    float* out = (float*)d_out;                 // [alpha, beta, gamma(4096)]
    (void)d_ws; (void)ws_size;

    // LDS: 2*CPAIR shorts (67.6K) + x2(512B) + y2(1K) = 69.1 KB -> 2 blocks/CU
    const int smem = 2 * CPAIR * 2 + (128 + 256) * (int)sizeof(float);
    (void)hipFuncSetAttribute((const void*)fused_dtw_kernel,
                              hipFuncAttributeMaxDynamicSharedMemorySize, smem);

    hipLaunchKernelGGL(fused_dtw_kernel, dim3(2048), dim3(128), smem, stream,
                       xs, xt, out + 2);
    hipLaunchKernelGGL(sinkhorn_kernel, dim3(1), dim3(64), 0, stream,
                       sim, out);
}